// Round 4
// baseline (123.281 us; speedup 1.0000x reference)
//
#include <hip/hip_runtime.h>

typedef long long i64;

// One thread per negative sample. 64 consecutive threads (one wave) share a
// positive triple, so pos[] reads are wave-uniform and L1-hot.
//
// OUTPUT DTYPE: reference returns (int64 neg, bool keep); harness materializes
// d_out as an int32 buffer (verified R2: float writes read back as int32 bit
// patterns -> absmax 1.2e9). Write int32.
//
// INPUT WIDTH: probed at runtime (R1 core dump ruled out blind int64; probe
// showed fault-free execution). pos int32-view word 3 is 0 iff storage is
// int64 (high half of rels[0]); >=1 if int32 (heads[1]).
template <typename T>
__device__ __forceinline__ void sample_body(
    const T* __restrict__ pos, const T* __restrict__ rand_vals,
    const T* __restrict__ table,
    int* __restrict__ out_neg, int* __restrict__ out_keep,
    unsigned i, int split, int L, unsigned num_negs)
{
    unsigned b = i / num_negs;   // num_negs=64 -> shift
    i64 h = (i64)pos[3 * b + 0];
    i64 r = (i64)pos[3 * b + 1];
    i64 t = (i64)pos[3 * b + 2];
    i64 rv = (i64)rand_vals[i];

    const bool corrupt_head = (i < (unsigned)split);
    i64 orig = corrupt_head ? h : t;
    // pad_idx==0 fast path: rng drawn in [1, NUM_ENTITIES); shift past original
    i64 repl = rv + (((rv >= orig) & (orig > 0)) ? 1 : 0);
    if (corrupt_head) h = repl; else t = repl;

    i64 key = (h << 42) | (r << 21) | t;

    // lower_bound (matches jnp.searchsorted side='left')
    int low = 0, size = L;
    while (size > 0) {
        int half = size >> 1;
        int mid = low + half;
        i64 v = (i64)table[mid];
        if (v < key) { low = mid + 1; size -= half + 1; }
        else         { size = half; }
    }
    bool in_set = (low < L) && ((i64)table[low] == key);

    out_neg[3 * (size_t)i + 0] = (int)h;
    out_neg[3 * (size_t)i + 1] = (int)r;
    out_neg[3 * (size_t)i + 2] = (int)t;
    out_keep[i] = in_set ? 0 : 1;
}

__global__ __launch_bounds__(256) void neg_sample_kernel(
    const void* __restrict__ pos, const void* __restrict__ rand_vals,
    const void* __restrict__ table,
    int* __restrict__ out_neg, int* __restrict__ out_keep,
    int total, int split, int L, unsigned num_negs)
{
    unsigned i = blockIdx.x * blockDim.x + threadIdx.x;
    if (i >= (unsigned)total) return;

    const int* pw = (const int*)pos;
    const bool is64 = (pw[3] == 0);   // wave-uniform, L1-hot

    if (is64) {
        sample_body<i64>((const i64*)pos, (const i64*)rand_vals, (const i64*)table,
                         out_neg, out_keep, i, split, L, num_negs);
    } else {
        sample_body<int>((const int*)pos, (const int*)rand_vals, (const int*)table,
                         out_neg, out_keep, i, split, L, num_negs);
    }
}

extern "C" void kernel_launch(void* const* d_in, const int* in_sizes, int n_in,
                              void* d_out, int out_size, void* d_ws, size_t ws_size,
                              hipStream_t stream) {
    const void* pos       = d_in[0];
    const void* rand_vals = d_in[1];
    const void* table     = d_in[2];
    // d_in[3] is the num_negs scalar on device; derive from sizes instead.

    const int B     = in_sizes[0] / 3;
    const int total = in_sizes[1];
    const int L     = in_sizes[2];
    const unsigned num_negs = (unsigned)(total / B);
    const int split = (total + 1) / 2;   // ceil(total/2) == -(-total//2)

    int* out_neg  = (int*)d_out;
    int* out_keep = out_neg + (size_t)total * 3;

    const int threads = 256;
    const int blocks  = (total + threads - 1) / threads;
    neg_sample_kernel<<<blocks, threads, 0, stream>>>(
        pos, rand_vals, table, out_neg, out_keep, total, split, L, num_negs);
}